// Round 7
// baseline (545.715 us; speedup 1.0000x reference)
//
#include <hip/hip_runtime.h>
#include <stdint.h>

// NSVF render. Round-7:
//  - 5 kernels: prep (frags+PE tables+counter zero), compact (atomic slot
//    reservation + per-ray view-PE), mlp_mfma, repair, render
//  - mlp: h1/h2 stored in LDS as bf16-RNE (2B) -> ds_read_b128 IS the A
//    operand (no unpack), 2-pass MFMA on L2/color, LDS 17.4 KB/block
//  - sigma repair threshold 0.02 (A-side rounding err ~3e-3)

#define NRAYS 8192
#define MAXS  64
#define EMB   32
#define HID   128
#define NPE   27
#define CH    64
#define NPTS  (NRAYS * MAXS)
#define RCAP  16384

// d_ws layout (float indices)
#define WS_WPE    0                        // [32][64] WPE[v*64+j] = Wc1[128+v][j]
#define WS_BCOMB  (WS_WPE + 32*CH)         // [64]
#define WS_CCINIT (WS_BCOMB + CH)          // [8192][64]
#define WS_TOTAL  (WS_CCINIT + NRAYS*CH)   // [1] int
#define WS_RCNT   (WS_TOTAL + 1)           // [1] int
#define WS_LIST   (WS_TOTAL + 4)           // [524288] int (16B aligned)
#define WS_PTOUT  (WS_LIST + NPTS)         // [524288] float4
#define WS_FRAGS  (WS_PTOUT + 4*NPTS)      // 56*2*64*4 ints
#define WS_RLIST  (WS_FRAGS + 56*2*64*4)   // [RCAP] int

typedef __attribute__((ext_vector_type(8))) short bf16x8;
typedef __attribute__((ext_vector_type(4))) float f32x4;
union FI { int i[4]; int4 v; bf16x8 f; };

#define MFMA16(a, b, c) __builtin_amdgcn_mfma_f32_16x16x32_bf16(a, b, c, 0, 0, 0)

__device__ __forceinline__ f32x4 mfma3(bf16x8 ah, bf16x8 al, bf16x8 bh, bf16x8 bl,
                                       f32x4 c) {
  c = MFMA16(al, bh, c);
  c = MFMA16(ah, bl, c);
  c = MFMA16(ah, bh, c);
  return c;
}

__device__ __forceinline__ void split8(const float* x, bf16x8& hi, bf16x8& lo) {
  FI H, L;
#pragma unroll
  for (int r = 0; r < 4; ++r) {
    unsigned u0 = __float_as_uint(x[2 * r]);
    unsigned u1 = __float_as_uint(x[2 * r + 1]);
    unsigned h0 = u0 & 0xffff0000u, h1 = u1 & 0xffff0000u;
    unsigned l0 = __float_as_uint(x[2 * r] - __uint_as_float(h0));
    unsigned l1 = __float_as_uint(x[2 * r + 1] - __uint_as_float(h1));
    H.i[r] = (int)((h0 >> 16) | (h1 & 0xffff0000u));
    L.i[r] = (int)((l0 >> 16) | (l1 & 0xffff0000u));
  }
  hi = H.f; lo = L.f;
}

__device__ __forceinline__ short bf16rne(float v) {
  unsigned u = __float_as_uint(v);
  u += 0x7fffu + ((u >> 16) & 1u);
  return (short)(u >> 16);
}

// ---------------- prep: PE tables + counter zero + all weight fragments ----
__global__ __launch_bounds__(256) void prep_kernel(
    const float* __restrict__ W1, const float* __restrict__ W2,
    const float* __restrict__ Wfeat, const float* __restrict__ bfeat,
    const float* __restrict__ Wc1, const float* __restrict__ bc1,
    float* __restrict__ ws) {
  int idx = blockIdx.x * 256 + threadIdx.x;
  if (idx < 32 * CH) {                         // WPE v-major [v][j]
    int v = idx >> 6, j = idx & 63;
    ws[WS_WPE + idx] = (v < NPE) ? Wc1[(HID + v) * CH + j] : 0.f;
    return;
  }
  idx -= 32 * CH;
  if (idx < CH) {                              // bcomb
    float s = bc1[idx];
    for (int f = 0; f < HID; ++f) s = fmaf(bfeat[f], Wc1[f * CH + idx], s);
    ws[WS_BCOMB + idx] = s;
    return;
  }
  idx -= CH;
  if (idx < 2) {                               // zero counters
    ((int*)(ws + WS_TOTAL))[idx] = 0;          // WS_TOTAL, WS_RCNT
    return;
  }
  idx -= 2;
  if (idx >= 56 * 64) return;                  // B fragments
  const int fid = idx >> 6, lane = idx & 63;
  const int n16 = lane & 15, quad = lane >> 4;
  float x[8];
  if (fid < 8) {                       // L1: W1[k][n], K=32
    const int n = fid * 16 + n16, k0 = quad * 8;
#pragma unroll
    for (int j = 0; j < 8; ++j) x[j] = W1[(k0 + j) * HID + n];
  } else if (fid < 40) {               // L2: fid = 8 + nt*4 + s
    const int f = fid - 8, nt = f >> 2, s = f & 3;
    const int n = nt * 16 + n16, k0 = s * 32 + quad * 8;
#pragma unroll
    for (int j = 0; j < 8; ++j) x[j] = W2[(k0 + j) * HID + n];
  } else {                             // Wcomb frags: compute dot on the fly
    const int f = fid - 40, nt = f >> 2, s = f & 3;
    const int n = nt * 16 + n16, k0 = s * 32 + quad * 8;
#pragma unroll
    for (int j = 0; j < 8; ++j) {
      float sum = 0.f;
      const float* wf = Wfeat + (k0 + j) * HID;
      for (int ff = 0; ff < HID; ++ff) sum = fmaf(wf[ff], Wc1[ff * CH + n], sum);
      x[j] = sum;
    }
  }
  FI H, L;
#pragma unroll
  for (int r = 0; r < 4; ++r) {
    unsigned u0 = __float_as_uint(x[2 * r]);
    unsigned u1 = __float_as_uint(x[2 * r + 1]);
    unsigned h0 = u0 & 0xffff0000u, h1 = u1 & 0xffff0000u;
    unsigned l0 = __float_as_uint(x[2 * r] - __uint_as_float(h0));
    unsigned l1 = __float_as_uint(x[2 * r + 1] - __uint_as_float(h1));
    H.i[r] = (int)((h0 >> 16) | (h1 & 0xffff0000u));
    L.i[r] = (int)((l0 >> 16) | (l1 & 0xffff0000u));
  }
  int4* o = (int4*)(ws + WS_FRAGS);
  o[(fid * 2 + 0) * 64 + lane] = H.v;
  o[(fid * 2 + 1) * 64 + lane] = L.v;
}

// ---------------- compact: list via atomic reservation + per-ray view PE ---
__global__ __launch_bounds__(256) void compact_kernel(
    const float* __restrict__ rays_d, const int* __restrict__ p2v,
    float* __restrict__ ws) {
  const int tid = threadIdx.x;
  const int ray = blockIdx.x * 4 + (tid >> 6);
  const int lane = tid & 63;
  const int pidx = ray * MAXS + lane;
  const bool valid = p2v[pidx] >= 0;
  const unsigned long long ball = __ballot(valid);
  const int cnt = __popcll(ball);
  int off = 0;
  if (lane == 0 && cnt) off = atomicAdd((int*)(ws + WS_TOTAL), cnt);
  off = __shfl(off, 0, 64);
  const int rank = __popcll(ball & ((1ull << lane) - 1ull));
  if (valid) ((int*)(ws + WS_LIST))[off + rank] = pidx;

  // per-ray view-PE -> ccinit[ray][lane]
  const float d0 = rays_d[ray * 3 + 0];
  const float d1 = rays_d[ray * 3 + 1];
  const float d2 = rays_d[ray * 3 + 2];
  float vemb[NPE];
  vemb[0] = d0; vemb[1] = d1; vemb[2] = d2;
#pragma unroll
  for (int i = 0; i < 3; ++i) {
    const float di = (i == 0) ? d0 : (i == 1) ? d1 : d2;
#pragma unroll
    for (int l = 0; l < 4; ++l) {
      const float ang = di * (float)(1 << l);
      vemb[3 + i * 4 + l] = __sinf(ang);
      vemb[3 + 12 + i * 4 + l] = __cosf(ang);
    }
  }
  float s = ws[WS_BCOMB + lane];
  const float* wpe = ws + WS_WPE;
#pragma unroll
  for (int v = 0; v < NPE; ++v) s = fmaf(vemb[v], wpe[v * CH + lane], s);
  ws[WS_CCINIT + ray * CH + lane] = s;
}

// ---------------- MFMA MLP ----------------
__device__ __forceinline__ void ve_frag(const float* __restrict__ pts,
                                        const float* __restrict__ vox_emb,
                                        const float* __restrict__ Wpts,
                                        int pidx, int gidx, int quad,
                                        bf16x8& hi, bf16x8& lo) {
  float x[8];
  const float4* vr = (const float4*)vox_emb + gidx * 8 + quad * 2;
  const float4 va = vr[0], vb = vr[1];
  const float px = pts[pidx * 3 + 0];
  const float py = pts[pidx * 3 + 1];
  const float pz = pts[pidx * 3 + 2];
  const float4* wp = (const float4*)Wpts;
  const float4 wa0 = wp[quad * 2 + 0], wa1 = wp[quad * 2 + 1];
  const float4 wb0 = wp[8 + quad * 2 + 0], wb1 = wp[8 + quad * 2 + 1];
  const float4 wc0 = wp[16 + quad * 2 + 0], wc1 = wp[16 + quad * 2 + 1];
  x[0] = va.x + fmaf(px, wa0.x, fmaf(py, wb0.x, pz * wc0.x));
  x[1] = va.y + fmaf(px, wa0.y, fmaf(py, wb0.y, pz * wc0.y));
  x[2] = va.z + fmaf(px, wa0.z, fmaf(py, wb0.z, pz * wc0.z));
  x[3] = va.w + fmaf(px, wa0.w, fmaf(py, wb0.w, pz * wc0.w));
  x[4] = vb.x + fmaf(px, wa1.x, fmaf(py, wb1.x, pz * wc1.x));
  x[5] = vb.y + fmaf(px, wa1.y, fmaf(py, wb1.y, pz * wc1.y));
  x[6] = vb.z + fmaf(px, wa1.z, fmaf(py, wb1.z, pz * wc1.z));
  x[7] = vb.w + fmaf(px, wa1.w, fmaf(py, wb1.w, pz * wc1.w));
  split8(x, hi, lo);
}

#define SSTR 136   // shorts per LDS row (136*2B = 272B = 17 x 16B units)

__global__ __launch_bounds__(128, 2) void mlp_mfma(
    const float* __restrict__ pts, const int* __restrict__ p2v,
    const float* __restrict__ vox_emb, const float* __restrict__ Wpts,
    const float* __restrict__ b1, const float* __restrict__ b2,
    const float* __restrict__ Wsig, const float* __restrict__ bsig,
    const float* __restrict__ Wc2, const float* __restrict__ bc2,
    float* __restrict__ ws) {
  __shared__ short alds[2 * 32 * SSTR];  // 17408 B
  const int tid = threadIdx.x;
  const int wave = tid >> 6, lane = tid & 63;
  const int n16 = lane & 15, quad = lane >> 4;
  const int total = ((const int*)(ws + WS_TOTAL))[0];
  const int base = blockIdx.x * 64 + wave * 32;
  if (base >= total) return;
  const int* list = (const int*)(ws + WS_LIST);
  const int pidx0 = list[min(base + n16, total - 1)];
  const int pidx1 = list[min(base + 16 + n16, total - 1)];
  const int4* fb = (const int4*)(ws + WS_FRAGS);
  const int wavebase = wave * 32 * SSTR;

  // ---- prefetch L1 B fragments
  int4 B1f[16];
#pragma unroll
  for (int i = 0; i < 16; ++i) B1f[i] = fb[i * 64 + lane];

  // ---- A-fragments for ve
  bf16x8 a0h, a0l, a1h, a1l;
  ve_frag(pts, vox_emb, Wpts, pidx0, p2v[pidx0], quad, a0h, a0l);
  ve_frag(pts, vox_emb, Wpts, pidx1, p2v[pidx1], quad, a1h, a1l);

  // ---- prefetch L2 s=0
  int4 BL[2][16];
#pragma unroll
  for (int nt = 0; nt < 8; ++nt) {
    BL[0][2 * nt]     = fb[((8 + nt * 4) * 2 + 0) * 64 + lane];
    BL[0][2 * nt + 1] = fb[((8 + nt * 4) * 2 + 1) * 64 + lane];
  }

  // ---- L1: h1 = relu(ve @ W1 + b1) (3-pass), store bf16-RNE to LDS
  f32x4 h[2][8];
#pragma unroll
  for (int nt = 0; nt < 8; ++nt) {
    const float bb = b1[nt * 16 + n16];
    h[0][nt] = (f32x4){bb, bb, bb, bb};
    h[1][nt] = h[0][nt];
  }
#pragma unroll
  for (int nt = 0; nt < 8; ++nt) {
    FI H, L; H.v = B1f[2 * nt]; L.v = B1f[2 * nt + 1];
    h[0][nt] = mfma3(a0h, a0l, H.f, L.f, h[0][nt]);
    h[1][nt] = mfma3(a1h, a1l, H.f, L.f, h[1][nt]);
  }
#pragma unroll
  for (int mt = 0; mt < 2; ++mt)
#pragma unroll
    for (int nt = 0; nt < 8; ++nt)
#pragma unroll
      for (int r = 0; r < 4; ++r)
        alds[wavebase + (mt * 16 + quad * 4 + r) * SSTR + nt * 16 + n16] =
            bf16rne(fmaxf(h[mt][nt][r], 0.f));

  // ---- L2: h2 = relu(h1 @ W2 + b2), 2-pass MFMA, double-buffered B
  f32x4 g[2][8];
#pragma unroll
  for (int nt = 0; nt < 8; ++nt) {
    const float bb = b2[nt * 16 + n16];
    g[0][nt] = (f32x4){bb, bb, bb, bb};
    g[1][nt] = g[0][nt];
  }
#pragma unroll
  for (int s = 0; s < 4; ++s) {
    if (s < 3) {
#pragma unroll
      for (int nt = 0; nt < 8; ++nt) {
        BL[(s + 1) & 1][2 * nt]     = fb[((8 + nt * 4 + s + 1) * 2 + 0) * 64 + lane];
        BL[(s + 1) & 1][2 * nt + 1] = fb[((8 + nt * 4 + s + 1) * 2 + 1) * 64 + lane];
      }
    }
    const bf16x8 A0 = *(const bf16x8*)(alds + wavebase + n16 * SSTR + s * 32 + quad * 8);
    const bf16x8 A1 = *(const bf16x8*)(alds + wavebase + (16 + n16) * SSTR + s * 32 + quad * 8);
#pragma unroll
    for (int nt = 0; nt < 8; ++nt) {
      FI H, L; H.v = BL[s & 1][2 * nt]; L.v = BL[s & 1][2 * nt + 1];
      g[0][nt] = MFMA16(A0, L.f, g[0][nt]);
      g[0][nt] = MFMA16(A0, H.f, g[0][nt]);
      g[1][nt] = MFMA16(A1, L.f, g[1][nt]);
      g[1][nt] = MFMA16(A1, H.f, g[1][nt]);
    }
  }

  // ---- prefetch color s=0 + ccinit; sigma epilogue overlaps
  int pm[2][4];
#pragma unroll
  for (int mt = 0; mt < 2; ++mt)
#pragma unroll
    for (int r = 0; r < 4; ++r)
      pm[mt][r] = __shfl(mt ? pidx1 : pidx0, quad * 4 + r, 64);
  int4 BC[2][8];
#pragma unroll
  for (int nt = 0; nt < 4; ++nt) {
    BC[0][2 * nt]     = fb[((40 + nt * 4) * 2 + 0) * 64 + lane];
    BC[0][2 * nt + 1] = fb[((40 + nt * 4) * 2 + 1) * 64 + lane];
  }
  f32x4 cacc[2][4];
#pragma unroll
  for (int mt = 0; mt < 2; ++mt)
#pragma unroll
    for (int nt = 0; nt < 4; ++nt)
#pragma unroll
      for (int r = 0; r < 4; ++r)
        cacc[mt][nt][r] = ws[WS_CCINIT + (pm[mt][r] >> 6) * CH + nt * 16 + n16];

  float sg[2][4] = {{0.f, 0.f, 0.f, 0.f}, {0.f, 0.f, 0.f, 0.f}};
#pragma unroll
  for (int nt = 0; nt < 8; ++nt) {
    const float sv = Wsig[nt * 16 + n16];
#pragma unroll
    for (int mt = 0; mt < 2; ++mt)
#pragma unroll
      for (int r = 0; r < 4; ++r) {
        const float v = fmaxf(g[mt][nt][r], 0.f);
        sg[mt][r] = fmaf(v, sv, sg[mt][r]);
        alds[wavebase + (mt * 16 + quad * 4 + r) * SSTR + nt * 16 + n16] = bf16rne(v);
      }
  }
#pragma unroll
  for (int mask = 1; mask < 16; mask <<= 1)
#pragma unroll
    for (int mt = 0; mt < 2; ++mt)
#pragma unroll
      for (int r = 0; r < 4; ++r) sg[mt][r] += __shfl_xor(sg[mt][r], mask, 64);

  // ---- color: cc = ccinit + h2 @ Wcomb, 2-pass MFMA
#pragma unroll
  for (int s = 0; s < 4; ++s) {
    if (s < 3) {
#pragma unroll
      for (int nt = 0; nt < 4; ++nt) {
        BC[(s + 1) & 1][2 * nt]     = fb[((40 + nt * 4 + s + 1) * 2 + 0) * 64 + lane];
        BC[(s + 1) & 1][2 * nt + 1] = fb[((40 + nt * 4 + s + 1) * 2 + 1) * 64 + lane];
      }
    }
    const bf16x8 A0 = *(const bf16x8*)(alds + wavebase + n16 * SSTR + s * 32 + quad * 8);
    const bf16x8 A1 = *(const bf16x8*)(alds + wavebase + (16 + n16) * SSTR + s * 32 + quad * 8);
#pragma unroll
    for (int nt = 0; nt < 4; ++nt) {
      FI H, L; H.v = BC[s & 1][2 * nt]; L.v = BC[s & 1][2 * nt + 1];
      cacc[0][nt] = MFMA16(A0, L.f, cacc[0][nt]);
      cacc[0][nt] = MFMA16(A0, H.f, cacc[0][nt]);
      cacc[1][nt] = MFMA16(A1, L.f, cacc[1][nt]);
      cacc[1][nt] = MFMA16(A1, H.f, cacc[1][nt]);
    }
  }

  // ---- rgb = relu(cc) @ Wc2 + bc2
  float cr[2][3][4];
#pragma unroll
  for (int mt = 0; mt < 2; ++mt)
#pragma unroll
    for (int c = 0; c < 3; ++c)
#pragma unroll
      for (int r = 0; r < 4; ++r) cr[mt][c][r] = 0.f;
#pragma unroll
  for (int nt = 0; nt < 4; ++nt) {
    const int j = nt * 16 + n16;
    const float w0 = Wc2[j * 3 + 0], w1c = Wc2[j * 3 + 1], w2c = Wc2[j * 3 + 2];
#pragma unroll
    for (int mt = 0; mt < 2; ++mt)
#pragma unroll
      for (int r = 0; r < 4; ++r) {
        const float cv = fmaxf(cacc[mt][nt][r], 0.f);
        cr[mt][0][r] = fmaf(cv, w0, cr[mt][0][r]);
        cr[mt][1][r] = fmaf(cv, w1c, cr[mt][1][r]);
        cr[mt][2][r] = fmaf(cv, w2c, cr[mt][2][r]);
      }
  }
#pragma unroll
  for (int mask = 1; mask < 16; mask <<= 1)
#pragma unroll
    for (int mt = 0; mt < 2; ++mt)
#pragma unroll
      for (int c = 0; c < 3; ++c)
#pragma unroll
        for (int r = 0; r < 4; ++r) cr[mt][c][r] += __shfl_xor(cr[mt][c][r], mask, 64);

  if (n16 == 0) {
    const float bs = bsig[0];
    const float bcr = bc2[0], bcg = bc2[1], bcb = bc2[2];
#pragma unroll
    for (int mt = 0; mt < 2; ++mt)
#pragma unroll
      for (int r = 0; r < 4; ++r) {
        const int m = mt * 16 + quad * 4 + r;
        if (base + m < total) {
          const int pid = pm[mt][r];
          const float sig = sg[mt][r] + bs;
          ((float4*)(ws + WS_PTOUT))[pid] =
              make_float4(sig, cr[mt][0][r] + bcr, cr[mt][1][r] + bcg, cr[mt][2][r] + bcb);
          if (fabsf(sig) < 0.02f) {
            const int ri = atomicAdd((int*)(ws + WS_RCNT), 1);
            if (ri < RCAP) ((int*)(ws + WS_RLIST))[ri] = pid;
          }
        }
      }
  }
}

// ---------------- sigma repair: wave-per-point f32 recompute ----------------
__device__ __forceinline__ float wave_sum(float v) {
#pragma unroll
  for (int off = 32; off > 0; off >>= 1) v += __shfl_down(v, off, 64);
  return v;
}

__global__ __launch_bounds__(256) void repair_kernel(
    const float* __restrict__ pts, const int* __restrict__ p2v,
    const float* __restrict__ vox_emb, const float* __restrict__ Wpts,
    const float* __restrict__ W1, const float* __restrict__ b1,
    const float* __restrict__ W2, const float* __restrict__ b2,
    const float* __restrict__ Wsig, const float* __restrict__ bsig,
    float* __restrict__ ws) {
  __shared__ float h1s[4][HID];
  const int wv = threadIdx.x >> 6, lane = threadIdx.x & 63;
  const int cnt = min(((const int*)(ws + WS_RCNT))[0], RCAP);
  const int nw = gridDim.x * 4;
  for (int i = blockIdx.x * 4 + wv; i < cnt; i += nw) {
    const int pidx = ((const int*)(ws + WS_RLIST))[i];
    const int gidx = p2v[pidx];   // wave-uniform
    const float px = pts[pidx * 3 + 0];
    const float py = pts[pidx * 3 + 1];
    const float pz = pts[pidx * 3 + 2];
    float ve[EMB];
#pragma unroll
    for (int e = 0; e < EMB; ++e)
      ve[e] = vox_emb[gidx * EMB + e] +
              fmaf(px, Wpts[e], fmaf(py, Wpts[EMB + e], pz * Wpts[2 * EMB + e]));
    float s0 = b1[lane], s1 = b1[lane + 64];
#pragma unroll
    for (int k = 0; k < EMB; ++k) {
      const float x = ve[k];
      s0 = fmaf(x, W1[k * HID + lane], s0);
      s1 = fmaf(x, W1[k * HID + lane + 64], s1);
    }
    h1s[wv][lane] = fmaxf(s0, 0.f);
    h1s[wv][lane + 64] = fmaxf(s1, 0.f);
    float t0 = b2[lane], t1 = b2[lane + 64];
    for (int k = 0; k < HID; ++k) {
      const float x = h1s[wv][k];
      t0 = fmaf(x, W2[k * HID + lane], t0);
      t1 = fmaf(x, W2[k * HID + lane + 64], t1);
    }
    float sp = fmaf(fmaxf(t0, 0.f), Wsig[lane], fmaxf(t1, 0.f) * Wsig[lane + 64]);
    sp = wave_sum(sp);
    if (lane == 0) ws[WS_PTOUT + 4 * pidx + 0] = sp + bsig[0];
  }
}

// ---------------- render ----------------
__device__ __forceinline__ float wave_prefix_excl(float v, int lane) {
  float inc = v;
#pragma unroll
  for (int off = 1; off < 64; off <<= 1) {
    float u = __shfl_up(inc, off, 64);
    if (lane >= off) inc += u;
  }
  return inc - v;
}

__global__ __launch_bounds__(256) void render_kernel(
    const float* __restrict__ t_vals, const float* __restrict__ dists,
    const int* __restrict__ p2v, const float* __restrict__ ws,
    float* __restrict__ out_rgb, float* __restrict__ out_disp,
    float* __restrict__ out_acc) {
  const int tid = threadIdx.x;
  const int ray = blockIdx.x * 4 + (tid >> 6);
  const int lane = tid & 63;
  const int pidx = ray * MAXS + lane;

  const int vidx = p2v[pidx];
  const bool hit = (__shfl(vidx, 0, 64) >= 0);
  if (!hit) {
    if (lane < 3) out_rgb[ray * 3 + lane] = 0.f;
    if (lane == 0) { out_disp[ray] = 0.f; out_acc[ray] = 0.f; }
    return;
  }
  const bool valid = vidx >= 0;

  const float4 pv = ((const float4*)(ws + WS_PTOUT))[pidx];
  const float fe = valid ? fmaxf(pv.x, 0.f) * dists[pidx] : 0.f;
  const float pref = wave_prefix_excl(fe, lane);
  const float T = __expf(-pref);
  const float w = (1.f - __expf(-fe)) * T;
  const float tv = t_vals[pidx];

  const float crgb0 = wave_sum(w * (pv.y + 1.f) * 0.5f);
  const float crgb1 = wave_sum(w * (pv.z + 1.f) * 0.5f);
  const float crgb2 = wave_sum(w * (pv.w + 1.f) * 0.5f);
  const float accs = wave_sum(w);
  const float depth = wave_sum(w * tv);

  if (lane == 0) {
    out_rgb[ray * 3 + 0] = crgb0;
    out_rgb[ray * 3 + 1] = crgb1;
    out_rgb[ray * 3 + 2] = crgb2;
    const float disp = 1.f / fmaxf(1e-10f, depth / fmaxf(accs, 1e-10f));
    out_disp[ray] = disp;
    out_acc[ray] = accs;
  }
}

extern "C" void kernel_launch(void* const* d_in, const int* in_sizes, int n_in,
                              void* d_out, int out_size, void* d_ws, size_t ws_size,
                              hipStream_t stream) {
  const float* rays_d  = (const float*)d_in[0];
  const float* pts     = (const float*)d_in[1];
  const float* t_vals  = (const float*)d_in[2];
  const float* dists   = (const float*)d_in[3];
  const int*   p2v     = (const int*)d_in[4];
  const float* vox_emb = (const float*)d_in[6];
  const float* Wpts    = (const float*)d_in[7];
  const float* W1      = (const float*)d_in[8];
  const float* b1      = (const float*)d_in[9];
  const float* W2      = (const float*)d_in[10];
  const float* b2      = (const float*)d_in[11];
  const float* Wsig    = (const float*)d_in[12];
  const float* bsig    = (const float*)d_in[13];
  const float* Wfeat   = (const float*)d_in[14];
  const float* bfeat   = (const float*)d_in[15];
  const float* Wc1     = (const float*)d_in[16];
  const float* bc1     = (const float*)d_in[17];
  const float* Wc2     = (const float*)d_in[18];
  const float* bc2     = (const float*)d_in[19];

  float* ws = (float*)d_ws;
  float* out = (float*)d_out;
  float* out_rgb = out;
  float* out_disp = out + NRAYS * 3;
  float* out_acc = out + NRAYS * 4;

  // prep threads: 2048 (WPE) + 64 (bcomb) + 2 (counters) + 3584 (frags) = 5698
  hipLaunchKernelGGL(prep_kernel, dim3(23), dim3(256), 0, stream,
                     W1, W2, Wfeat, bfeat, Wc1, bc1, ws);
  hipLaunchKernelGGL(compact_kernel, dim3(NRAYS / 4), dim3(256), 0, stream,
                     rays_d, p2v, ws);
  hipLaunchKernelGGL(mlp_mfma, dim3(NPTS / 64), dim3(128), 0, stream,
                     pts, p2v, vox_emb, Wpts, b1, b2, Wsig, bsig, Wc2, bc2, ws);
  hipLaunchKernelGGL(repair_kernel, dim3(128), dim3(256), 0, stream,
                     pts, p2v, vox_emb, Wpts, W1, b1, W2, b2, Wsig, bsig, ws);
  hipLaunchKernelGGL(render_kernel, dim3(NRAYS / 4), dim3(256), 0, stream,
                     t_vals, dists, p2v, ws, out_rgb, out_disp, out_acc);
}

// Round 8
// 260.518 us; speedup vs baseline: 2.0947x; 2.0947x over previous
//
#include <hip/hip_runtime.h>
#include <stdint.h>

// NSVF render. Round-8 = Round-6 (known-good 296us) + one attributable change:
//  - list_kernel also writes compacted ptsc[slot]=(px,py,pz,gidx) so mlp_mfma's
//    pts/p2v gathers become fully coalesced reads (scatter moved to the
//    memory-parallel list kernel where latency is absorbed).
//  - pe merged into count_kernel (-1 dispatch); dead W1T/W2T writes dropped.
//  - numerics identical to Round 6 (3-pass split-bf16 MFMA, packed hi|lo LDS,
//    repair threshold 0.006).

#define NRAYS 8192
#define MAXS  64
#define EMB   32
#define HID   128
#define NPE   27
#define CH    64
#define NPTS  (NRAYS * MAXS)
#define RCAP  16384

// d_ws layout (float indices)
#define WS_WCOMB  0                        // [128][64] f32 (prep -> prep2)
#define WS_WPE    (WS_WCOMB + HID*CH)      // [32][64]
#define WS_BCOMB  (WS_WPE + 32*CH)         // [64]
#define WS_CCINIT (WS_BCOMB + CH)          // [8192][64]
#define WS_COUNTS (WS_CCINIT + NRAYS*CH)   // [8192] int
#define WS_OFFS   (WS_COUNTS + NRAYS)      // [8192] int
#define WS_TOTAL  (WS_OFFS + NRAYS)        // [1] int
#define WS_RCNT   (WS_TOTAL + 1)           // [1] int
#define WS_LIST   (WS_TOTAL + 4)           // [NPTS] int (16B aligned)
#define WS_PTOUT  (WS_LIST + NPTS)         // [NPTS] float4
#define WS_FRAGS  (WS_PTOUT + 4*NPTS)      // 56*2*64*4 ints
#define WS_RLIST  (WS_FRAGS + 56*2*64*4)   // [RCAP] int
#define WS_PTSC   (WS_RLIST + RCAP)        // [NPTS] float4 (16B aligned)

typedef __attribute__((ext_vector_type(8))) short bf16x8;
typedef __attribute__((ext_vector_type(4))) float f32x4;
union FI { int i[4]; int4 v; bf16x8 f; };

#define MFMA16(a, b, c) __builtin_amdgcn_mfma_f32_16x16x32_bf16(a, b, c, 0, 0, 0)

__device__ __forceinline__ f32x4 mfma3(bf16x8 ah, bf16x8 al, bf16x8 bh, bf16x8 bl,
                                       f32x4 c) {
  c = MFMA16(al, bh, c);
  c = MFMA16(ah, bl, c);
  c = MFMA16(ah, bh, c);
  return c;
}

__device__ __forceinline__ void split8(const float* x, bf16x8& hi, bf16x8& lo) {
  FI H, L;
#pragma unroll
  for (int r = 0; r < 4; ++r) {
    unsigned u0 = __float_as_uint(x[2 * r]);
    unsigned u1 = __float_as_uint(x[2 * r + 1]);
    unsigned h0 = u0 & 0xffff0000u, h1 = u1 & 0xffff0000u;
    unsigned l0 = __float_as_uint(x[2 * r] - __uint_as_float(h0));
    unsigned l1 = __float_as_uint(x[2 * r + 1] - __uint_as_float(h1));
    H.i[r] = (int)((h0 >> 16) | (h1 & 0xffff0000u));
    L.i[r] = (int)((l0 >> 16) | (l1 & 0xffff0000u));
  }
  hi = H.f; lo = L.f;
}

// packed LDS word: low16 = hi-bf16, high16 = lo-bf16
__device__ __forceinline__ int packword(float v) {
  unsigned u = __float_as_uint(v);
  unsigned hb = u & 0xffff0000u;
  unsigned lb = __float_as_uint(v - __uint_as_float(hb));
  return (int)((u >> 16) | (lb & 0xffff0000u));
}

__device__ __forceinline__ void unpack8(const int* w, bf16x8& hi, bf16x8& lo) {
  FI H, L;
#pragma unroll
  for (int r = 0; r < 4; ++r) {
    unsigned w0 = (unsigned)w[2 * r], w1 = (unsigned)w[2 * r + 1];
    H.i[r] = (int)((w0 & 0xffffu) | (w1 << 16));
    L.i[r] = (int)((w0 >> 16) | (w1 & 0xffff0000u));
  }
  hi = H.f; lo = L.f;
}

// ---------------- prep: Wcomb f32 + PE tables + counter zero ----------------
__global__ __launch_bounds__(256) void prep_kernel(
    const float* __restrict__ Wfeat, const float* __restrict__ bfeat,
    const float* __restrict__ Wc1, const float* __restrict__ bc1,
    float* __restrict__ ws) {
  int idx = blockIdx.x * 256 + threadIdx.x;
  if (idx < HID * CH) {                        // Wcomb f32 (m-major), 8192-way
    int m = idx >> 6, j = idx & 63;
    float s = 0.f;
    for (int f = 0; f < HID; ++f) s = fmaf(Wfeat[m * HID + f], Wc1[f * CH + j], s);
    ws[WS_WCOMB + idx] = s;
    return;
  }
  idx -= HID * CH;
  if (idx < 32 * CH) {                         // WPE v-major [v][j]
    int v = idx >> 6, j = idx & 63;
    ws[WS_WPE + idx] = (v < NPE) ? Wc1[(HID + v) * CH + j] : 0.f;
    return;
  }
  idx -= 32 * CH;
  if (idx < CH) {                              // bcomb
    float s = bc1[idx];
    for (int f = 0; f < HID; ++f) s = fmaf(bfeat[f], Wc1[f * CH + idx], s);
    ws[WS_BCOMB + idx] = s;
    return;
  }
  idx -= CH;
  if (idx < 2) ((int*)(ws + WS_TOTAL))[idx] = 0;  // WS_TOTAL unused slot + RCNT... (scan rewrites)
}

// build bf16 hi/lo B-fragments: frag elem j of lane (n16,quad) = B[k0+j][n]
__global__ __launch_bounds__(256) void prep2_kernel(
    const float* __restrict__ W1, const float* __restrict__ W2,
    float* __restrict__ ws) {
  int t = blockIdx.x * 256 + threadIdx.x;
  if (t >= 56 * 64) return;
  const int fid = t >> 6, lane = t & 63;
  const int n16 = lane & 15, quad = lane >> 4;
  float x[8];
  if (fid < 8) {                       // L1: W1[k][n], K=32
    const int n = fid * 16 + n16, k0 = quad * 8;
#pragma unroll
    for (int j = 0; j < 8; ++j) x[j] = W1[(k0 + j) * HID + n];
  } else if (fid < 40) {               // L2: fid = 8 + nt*4 + s
    const int f = fid - 8, nt = f >> 2, s = f & 3;
    const int n = nt * 16 + n16, k0 = s * 32 + quad * 8;
#pragma unroll
    for (int j = 0; j < 8; ++j) x[j] = W2[(k0 + j) * HID + n];
  } else {                             // Wcomb: fid = 40 + nt*4 + s
    const int f = fid - 40, nt = f >> 2, s = f & 3;
    const int n = nt * 16 + n16, k0 = s * 32 + quad * 8;
#pragma unroll
    for (int j = 0; j < 8; ++j) x[j] = ws[WS_WCOMB + (k0 + j) * CH + n];
  }
  FI H, L;
#pragma unroll
  for (int r = 0; r < 4; ++r) {
    unsigned u0 = __float_as_uint(x[2 * r]);
    unsigned u1 = __float_as_uint(x[2 * r + 1]);
    unsigned h0 = u0 & 0xffff0000u, h1 = u1 & 0xffff0000u;
    unsigned l0 = __float_as_uint(x[2 * r] - __uint_as_float(h0));
    unsigned l1 = __float_as_uint(x[2 * r + 1] - __uint_as_float(h1));
    H.i[r] = (int)((h0 >> 16) | (h1 & 0xffff0000u));
    L.i[r] = (int)((l0 >> 16) | (l1 & 0xffff0000u));
  }
  int4* o = (int4*)(ws + WS_FRAGS);
  o[(fid * 2 + 0) * 64 + lane] = H.v;
  o[(fid * 2 + 1) * 64 + lane] = L.v;
}

// ---------------- count + per-ray view-PE (merged) ----------------
__global__ __launch_bounds__(256) void count_pe_kernel(
    const float* __restrict__ rays_d, const int* __restrict__ p2v,
    float* __restrict__ ws) {
  const int tid = threadIdx.x;
  const int ray = blockIdx.x * 4 + (tid >> 6);
  const int lane = tid & 63;
  const int v = p2v[ray * MAXS + lane];
  const unsigned long long ball = __ballot(v >= 0);
  if (lane == 0) ((int*)(ws + WS_COUNTS))[ray] = __popcll(ball);

  // per-ray view-PE -> ccinit[ray][lane]
  const float d0 = rays_d[ray * 3 + 0];
  const float d1 = rays_d[ray * 3 + 1];
  const float d2 = rays_d[ray * 3 + 2];
  float vemb[NPE];
  vemb[0] = d0; vemb[1] = d1; vemb[2] = d2;
#pragma unroll
  for (int i = 0; i < 3; ++i) {
    const float di = (i == 0) ? d0 : (i == 1) ? d1 : d2;
#pragma unroll
    for (int l = 0; l < 4; ++l) {
      const float ang = di * (float)(1 << l);
      vemb[3 + i * 4 + l] = __sinf(ang);
      vemb[3 + 12 + i * 4 + l] = __cosf(ang);
    }
  }
  float s = ws[WS_BCOMB + lane];
  const float* wpe = ws + WS_WPE;
#pragma unroll
  for (int vv = 0; vv < NPE; ++vv) s = fmaf(vemb[vv], wpe[vv * CH + lane], s);
  ws[WS_CCINIT + ray * CH + lane] = s;
}

__global__ __launch_bounds__(1024) void scan_kernel(float* __restrict__ ws) {
  const int* counts = (const int*)(ws + WS_COUNTS);
  int* offs = (int*)(ws + WS_OFFS);
  int* totalp = (int*)(ws + WS_TOTAL);
  __shared__ int wsum[16];
  const int tid = threadIdx.x;
  const int lane = tid & 63;
  const int base = tid * 8;
  if (tid == 0) ((int*)(ws + WS_RCNT))[0] = 0;   // zero repair counter each launch
  int c[8], e[8];
  int run = 0;
#pragma unroll
  for (int i = 0; i < 8; ++i) { c[i] = counts[base + i]; e[i] = run; run += c[i]; }
  int inc = run;
#pragma unroll
  for (int off = 1; off < 64; off <<= 1) {
    int u = __shfl_up(inc, off, 64);
    if (lane >= off) inc += u;
  }
  const int wexcl = inc - run;
  if (lane == 63) wsum[tid >> 6] = inc;
  __syncthreads();
  if (tid < 16) {
    int v = wsum[tid];
    int inc2 = v;
#pragma unroll
    for (int off = 1; off < 16; off <<= 1) {
      int u = __shfl_up(inc2, off, 64);
      if (tid >= off) inc2 += u;
    }
    wsum[tid] = inc2 - v;
    if (tid == 15) totalp[0] = inc2;
  }
  __syncthreads();
  const int wbase = wsum[tid >> 6];
#pragma unroll
  for (int i = 0; i < 8; ++i) offs[base + i] = wbase + wexcl + e[i];
}

// ---------------- list + compacted point gather ----------------
__global__ __launch_bounds__(256) void list_kernel(
    const int* __restrict__ p2v, const float* __restrict__ pts,
    float* __restrict__ ws) {
  const int tid = threadIdx.x;
  const int ray = blockIdx.x * 4 + (tid >> 6);
  const int lane = tid & 63;
  const int pidx = ray * MAXS + lane;
  const int gidx = p2v[pidx];
  const bool valid = gidx >= 0;
  const unsigned long long ball = __ballot(valid);
  const int rank = __popcll(ball & ((1ull << lane) - 1ull));
  if (valid) {
    const int off = ((const int*)(ws + WS_OFFS))[ray];
    const int slot = off + rank;
    ((int*)(ws + WS_LIST))[slot] = pidx;
    // coalesced pts read (pidx contiguous within the wave), compacted write
    float4 pc;
    pc.x = pts[pidx * 3 + 0];
    pc.y = pts[pidx * 3 + 1];
    pc.z = pts[pidx * 3 + 2];
    pc.w = __int_as_float(gidx);
    ((float4*)(ws + WS_PTSC))[slot] = pc;
  }
}

// ---------------- MFMA MLP ----------------
__device__ __forceinline__ void ve_frag(const float* __restrict__ vox_emb,
                                        const float* __restrict__ Wpts,
                                        float4 pc, int quad,
                                        bf16x8& hi, bf16x8& lo) {
  float x[8];
  const int gidx = __float_as_int(pc.w);
  const float4* vr = (const float4*)vox_emb + gidx * 8 + quad * 2;
  const float4 va = vr[0], vb = vr[1];
  const float px = pc.x, py = pc.y, pz = pc.z;
  const float4* wp = (const float4*)Wpts;
  const float4 wa0 = wp[quad * 2 + 0], wa1 = wp[quad * 2 + 1];
  const float4 wb0 = wp[8 + quad * 2 + 0], wb1 = wp[8 + quad * 2 + 1];
  const float4 wc0 = wp[16 + quad * 2 + 0], wc1 = wp[16 + quad * 2 + 1];
  x[0] = va.x + fmaf(px, wa0.x, fmaf(py, wb0.x, pz * wc0.x));
  x[1] = va.y + fmaf(px, wa0.y, fmaf(py, wb0.y, pz * wc0.y));
  x[2] = va.z + fmaf(px, wa0.z, fmaf(py, wb0.z, pz * wc0.z));
  x[3] = va.w + fmaf(px, wa0.w, fmaf(py, wb0.w, pz * wc0.w));
  x[4] = vb.x + fmaf(px, wa1.x, fmaf(py, wb1.x, pz * wc1.x));
  x[5] = vb.y + fmaf(px, wa1.y, fmaf(py, wb1.y, pz * wc1.y));
  x[6] = vb.z + fmaf(px, wa1.z, fmaf(py, wb1.z, pz * wc1.z));
  x[7] = vb.w + fmaf(px, wa1.w, fmaf(py, wb1.w, pz * wc1.w));
  split8(x, hi, lo);
}

#define LSTRIDE 133   // odd word stride: b32 read/write patterns stay <=2-way

__global__ __launch_bounds__(128, 2) void mlp_mfma(
    const float* __restrict__ vox_emb, const float* __restrict__ Wpts,
    const float* __restrict__ b1, const float* __restrict__ b2,
    const float* __restrict__ Wsig, const float* __restrict__ bsig,
    const float* __restrict__ Wc2, const float* __restrict__ bc2,
    float* __restrict__ ws) {
  __shared__ int alds[64 * LSTRIDE];
  const int tid = threadIdx.x;
  const int wave = tid >> 6, lane = tid & 63;
  const int n16 = lane & 15, quad = lane >> 4;
  const int total = ((const int*)(ws + WS_TOTAL))[0];
  const int base = blockIdx.x * 64 + wave * 32;
  if (base >= total) return;
  const int* list = (const int*)(ws + WS_LIST);
  const int slot0 = min(base + n16, total - 1);
  const int slot1 = min(base + 16 + n16, total - 1);
  const int pidx0 = list[slot0];
  const int pidx1 = list[slot1];
  const float4 pc0 = ((const float4*)(ws + WS_PTSC))[slot0];  // coalesced
  const float4 pc1 = ((const float4*)(ws + WS_PTSC))[slot1];
  const int4* fb = (const int4*)(ws + WS_FRAGS);

  // ---- prefetch L1 B fragments (slots 0..15) before anything else
  int4 B1f[16];
#pragma unroll
  for (int i = 0; i < 16; ++i) B1f[i] = fb[i * 64 + lane];

  // ---- A-fragments for ve (vox gathers fly with B1f)
  bf16x8 a0h, a0l, a1h, a1l;
  ve_frag(vox_emb, Wpts, pc0, quad, a0h, a0l);
  ve_frag(vox_emb, Wpts, pc1, quad, a1h, a1l);

  // ---- prefetch L2 s=0 while L1 computes
  int4 BL[2][16];
#pragma unroll
  for (int nt = 0; nt < 8; ++nt) {
    BL[0][2 * nt]     = fb[((8 + nt * 4) * 2 + 0) * 64 + lane];
    BL[0][2 * nt + 1] = fb[((8 + nt * 4) * 2 + 1) * 64 + lane];
  }

  // ---- L1: h1 = relu(ve @ W1 + b1)
  f32x4 h[2][8];
#pragma unroll
  for (int nt = 0; nt < 8; ++nt) {
    const float bb = b1[nt * 16 + n16];
    h[0][nt] = (f32x4){bb, bb, bb, bb};
    h[1][nt] = h[0][nt];
  }
#pragma unroll
  for (int nt = 0; nt < 8; ++nt) {
    FI H, L; H.v = B1f[2 * nt]; L.v = B1f[2 * nt + 1];
    h[0][nt] = mfma3(a0h, a0l, H.f, L.f, h[0][nt]);
    h[1][nt] = mfma3(a1h, a1l, H.f, L.f, h[1][nt]);
  }
#pragma unroll
  for (int mt = 0; mt < 2; ++mt)
#pragma unroll
    for (int nt = 0; nt < 8; ++nt)
#pragma unroll
      for (int r = 0; r < 4; ++r) {
        const float v = fmaxf(h[mt][nt][r], 0.f);
        alds[(wave * 32 + mt * 16 + quad * 4 + r) * LSTRIDE + nt * 16 + n16] = packword(v);
      }

  // ---- L2: h2 = relu(h1 @ W2 + b2), double-buffered B
  f32x4 g[2][8];
#pragma unroll
  for (int nt = 0; nt < 8; ++nt) {
    const float bb = b2[nt * 16 + n16];
    g[0][nt] = (f32x4){bb, bb, bb, bb};
    g[1][nt] = g[0][nt];
  }
  const int rb0 = (wave * 32 + n16) * LSTRIDE;
  const int rb1 = rb0 + 16 * LSTRIDE;
#pragma unroll
  for (int s = 0; s < 4; ++s) {
    if (s < 3) {
#pragma unroll
      for (int nt = 0; nt < 8; ++nt) {
        BL[(s + 1) & 1][2 * nt]     = fb[((8 + nt * 4 + s + 1) * 2 + 0) * 64 + lane];
        BL[(s + 1) & 1][2 * nt + 1] = fb[((8 + nt * 4 + s + 1) * 2 + 1) * 64 + lane];
      }
    }
    int w0[8], w1[8];
#pragma unroll
    for (int j = 0; j < 8; ++j) {
      w0[j] = alds[rb0 + s * 32 + quad * 8 + j];
      w1[j] = alds[rb1 + s * 32 + quad * 8 + j];
    }
    bf16x8 A0h, A0l, A1h, A1l;
    unpack8(w0, A0h, A0l);
    unpack8(w1, A1h, A1l);
#pragma unroll
    for (int nt = 0; nt < 8; ++nt) {
      FI H, L; H.v = BL[s & 1][2 * nt]; L.v = BL[s & 1][2 * nt + 1];
      g[0][nt] = mfma3(A0h, A0l, H.f, L.f, g[0][nt]);
      g[1][nt] = mfma3(A1h, A1l, H.f, L.f, g[1][nt]);
    }
  }

  // ---- prefetch color s=0 + ccinit gathers; sigma epilogue overlaps them
  int pm[2][4];
#pragma unroll
  for (int mt = 0; mt < 2; ++mt)
#pragma unroll
    for (int r = 0; r < 4; ++r)
      pm[mt][r] = __shfl(mt ? pidx1 : pidx0, quad * 4 + r, 64);
  int4 BC[2][8];
#pragma unroll
  for (int nt = 0; nt < 4; ++nt) {
    BC[0][2 * nt]     = fb[((40 + nt * 4) * 2 + 0) * 64 + lane];
    BC[0][2 * nt + 1] = fb[((40 + nt * 4) * 2 + 1) * 64 + lane];
  }
  f32x4 cacc[2][4];
#pragma unroll
  for (int mt = 0; mt < 2; ++mt)
#pragma unroll
    for (int nt = 0; nt < 4; ++nt)
#pragma unroll
      for (int r = 0; r < 4; ++r)
        cacc[mt][nt][r] = ws[WS_CCINIT + (pm[mt][r] >> 6) * CH + nt * 16 + n16];

  float sg[2][4] = {{0.f, 0.f, 0.f, 0.f}, {0.f, 0.f, 0.f, 0.f}};
#pragma unroll
  for (int nt = 0; nt < 8; ++nt) {
    const float sv = Wsig[nt * 16 + n16];
#pragma unroll
    for (int mt = 0; mt < 2; ++mt)
#pragma unroll
      for (int r = 0; r < 4; ++r) {
        const float v = fmaxf(g[mt][nt][r], 0.f);
        sg[mt][r] = fmaf(v, sv, sg[mt][r]);
        alds[(wave * 32 + mt * 16 + quad * 4 + r) * LSTRIDE + nt * 16 + n16] = packword(v);
      }
  }
#pragma unroll
  for (int mask = 1; mask < 16; mask <<= 1)
#pragma unroll
    for (int mt = 0; mt < 2; ++mt)
#pragma unroll
      for (int r = 0; r < 4; ++r) sg[mt][r] += __shfl_xor(sg[mt][r], mask, 64);

  // ---- color: cc = ccinit + h2 @ Wcomb, double-buffered B
#pragma unroll
  for (int s = 0; s < 4; ++s) {
    if (s < 3) {
#pragma unroll
      for (int nt = 0; nt < 4; ++nt) {
        BC[(s + 1) & 1][2 * nt]     = fb[((40 + nt * 4 + s + 1) * 2 + 0) * 64 + lane];
        BC[(s + 1) & 1][2 * nt + 1] = fb[((40 + nt * 4 + s + 1) * 2 + 1) * 64 + lane];
      }
    }
    int w0[8], w1[8];
#pragma unroll
    for (int j = 0; j < 8; ++j) {
      w0[j] = alds[rb0 + s * 32 + quad * 8 + j];
      w1[j] = alds[rb1 + s * 32 + quad * 8 + j];
    }
    bf16x8 A0h, A0l, A1h, A1l;
    unpack8(w0, A0h, A0l);
    unpack8(w1, A1h, A1l);
#pragma unroll
    for (int nt = 0; nt < 4; ++nt) {
      FI H, L; H.v = BC[s & 1][2 * nt]; L.v = BC[s & 1][2 * nt + 1];
      cacc[0][nt] = mfma3(A0h, A0l, H.f, L.f, cacc[0][nt]);
      cacc[1][nt] = mfma3(A1h, A1l, H.f, L.f, cacc[1][nt]);
    }
  }

  // ---- rgb = relu(cc) @ Wc2 + bc2
  float cr[2][3][4];
#pragma unroll
  for (int mt = 0; mt < 2; ++mt)
#pragma unroll
    for (int c = 0; c < 3; ++c)
#pragma unroll
      for (int r = 0; r < 4; ++r) cr[mt][c][r] = 0.f;
#pragma unroll
  for (int nt = 0; nt < 4; ++nt) {
    const int j = nt * 16 + n16;
    const float w0 = Wc2[j * 3 + 0], w1c = Wc2[j * 3 + 1], w2c = Wc2[j * 3 + 2];
#pragma unroll
    for (int mt = 0; mt < 2; ++mt)
#pragma unroll
      for (int r = 0; r < 4; ++r) {
        const float cv = fmaxf(cacc[mt][nt][r], 0.f);
        cr[mt][0][r] = fmaf(cv, w0, cr[mt][0][r]);
        cr[mt][1][r] = fmaf(cv, w1c, cr[mt][1][r]);
        cr[mt][2][r] = fmaf(cv, w2c, cr[mt][2][r]);
      }
  }
#pragma unroll
  for (int mask = 1; mask < 16; mask <<= 1)
#pragma unroll
    for (int mt = 0; mt < 2; ++mt)
#pragma unroll
      for (int c = 0; c < 3; ++c)
#pragma unroll
        for (int r = 0; r < 4; ++r) cr[mt][c][r] += __shfl_xor(cr[mt][c][r], mask, 64);

  if (n16 == 0) {
    const float bs = bsig[0];
    const float bcr = bc2[0], bcg = bc2[1], bcb = bc2[2];
#pragma unroll
    for (int mt = 0; mt < 2; ++mt)
#pragma unroll
      for (int r = 0; r < 4; ++r) {
        const int m = mt * 16 + quad * 4 + r;
        if (base + m < total) {
          const int pid = pm[mt][r];
          const float sig = sg[mt][r] + bs;
          ((float4*)(ws + WS_PTOUT))[pid] =
              make_float4(sig, cr[mt][0][r] + bcr, cr[mt][1][r] + bcg, cr[mt][2][r] + bcb);
          if (fabsf(sig) < 0.006f) {
            const int ri = atomicAdd((int*)(ws + WS_RCNT), 1);
            if (ri < RCAP) ((int*)(ws + WS_RLIST))[ri] = pid;
          }
        }
      }
  }
}

// ---------------- sigma repair: wave-per-point f32 recompute ----------------
__device__ __forceinline__ float wave_sum(float v) {
#pragma unroll
  for (int off = 32; off > 0; off >>= 1) v += __shfl_down(v, off, 64);
  return v;
}

__global__ __launch_bounds__(256) void repair_kernel(
    const float* __restrict__ pts, const int* __restrict__ p2v,
    const float* __restrict__ vox_emb, const float* __restrict__ Wpts,
    const float* __restrict__ W1, const float* __restrict__ b1,
    const float* __restrict__ W2, const float* __restrict__ b2,
    const float* __restrict__ Wsig, const float* __restrict__ bsig,
    float* __restrict__ ws) {
  __shared__ float h1s[4][HID];
  const int wv = threadIdx.x >> 6, lane = threadIdx.x & 63;
  const int cnt = min(((const int*)(ws + WS_RCNT))[0], RCAP);
  const int nw = gridDim.x * 4;
  for (int i = blockIdx.x * 4 + wv; i < cnt; i += nw) {
    const int pidx = ((const int*)(ws + WS_RLIST))[i];
    const int gidx = p2v[pidx];   // wave-uniform
    const float px = pts[pidx * 3 + 0];
    const float py = pts[pidx * 3 + 1];
    const float pz = pts[pidx * 3 + 2];
    float ve[EMB];
#pragma unroll
    for (int e = 0; e < EMB; ++e)
      ve[e] = vox_emb[gidx * EMB + e] +
              fmaf(px, Wpts[e], fmaf(py, Wpts[EMB + e], pz * Wpts[2 * EMB + e]));
    float s0 = b1[lane], s1 = b1[lane + 64];
#pragma unroll
    for (int k = 0; k < EMB; ++k) {
      const float x = ve[k];
      s0 = fmaf(x, W1[k * HID + lane], s0);
      s1 = fmaf(x, W1[k * HID + lane + 64], s1);
    }
    h1s[wv][lane] = fmaxf(s0, 0.f);
    h1s[wv][lane + 64] = fmaxf(s1, 0.f);
    float t0 = b2[lane], t1 = b2[lane + 64];
    for (int k = 0; k < HID; ++k) {
      const float x = h1s[wv][k];
      t0 = fmaf(x, W2[k * HID + lane], t0);
      t1 = fmaf(x, W2[k * HID + lane + 64], t1);
    }
    float sp = fmaf(fmaxf(t0, 0.f), Wsig[lane], fmaxf(t1, 0.f) * Wsig[lane + 64]);
    sp = wave_sum(sp);
    if (lane == 0) ws[WS_PTOUT + 4 * pidx + 0] = sp + bsig[0];
  }
}

// ---------------- render ----------------
__device__ __forceinline__ float wave_prefix_excl(float v, int lane) {
  float inc = v;
#pragma unroll
  for (int off = 1; off < 64; off <<= 1) {
    float u = __shfl_up(inc, off, 64);
    if (lane >= off) inc += u;
  }
  return inc - v;
}

__global__ __launch_bounds__(256) void render_kernel(
    const float* __restrict__ t_vals, const float* __restrict__ dists,
    const int* __restrict__ p2v, const float* __restrict__ ws,
    float* __restrict__ out_rgb, float* __restrict__ out_disp,
    float* __restrict__ out_acc) {
  const int tid = threadIdx.x;
  const int ray = blockIdx.x * 4 + (tid >> 6);
  const int lane = tid & 63;
  const int pidx = ray * MAXS + lane;

  const int vidx = p2v[pidx];
  const bool hit = (__shfl(vidx, 0, 64) >= 0);
  if (!hit) {
    if (lane < 3) out_rgb[ray * 3 + lane] = 0.f;
    if (lane == 0) { out_disp[ray] = 0.f; out_acc[ray] = 0.f; }
    return;
  }
  const bool valid = vidx >= 0;

  const float4 pv = ((const float4*)(ws + WS_PTOUT))[pidx];
  const float fe = valid ? fmaxf(pv.x, 0.f) * dists[pidx] : 0.f;
  const float pref = wave_prefix_excl(fe, lane);
  const float T = __expf(-pref);
  const float w = (1.f - __expf(-fe)) * T;
  const float tv = t_vals[pidx];

  const float crgb0 = wave_sum(w * (pv.y + 1.f) * 0.5f);
  const float crgb1 = wave_sum(w * (pv.z + 1.f) * 0.5f);
  const float crgb2 = wave_sum(w * (pv.w + 1.f) * 0.5f);
  const float accs = wave_sum(w);
  const float depth = wave_sum(w * tv);

  if (lane == 0) {
    out_rgb[ray * 3 + 0] = crgb0;
    out_rgb[ray * 3 + 1] = crgb1;
    out_rgb[ray * 3 + 2] = crgb2;
    const float disp = 1.f / fmaxf(1e-10f, depth / fmaxf(accs, 1e-10f));
    out_disp[ray] = disp;
    out_acc[ray] = accs;
  }
}

extern "C" void kernel_launch(void* const* d_in, const int* in_sizes, int n_in,
                              void* d_out, int out_size, void* d_ws, size_t ws_size,
                              hipStream_t stream) {
  const float* rays_d  = (const float*)d_in[0];
  const float* pts     = (const float*)d_in[1];
  const float* t_vals  = (const float*)d_in[2];
  const float* dists   = (const float*)d_in[3];
  const int*   p2v     = (const int*)d_in[4];
  const float* vox_emb = (const float*)d_in[6];
  const float* Wpts    = (const float*)d_in[7];
  const float* W1      = (const float*)d_in[8];
  const float* b1      = (const float*)d_in[9];
  const float* W2      = (const float*)d_in[10];
  const float* b2      = (const float*)d_in[11];
  const float* Wsig    = (const float*)d_in[12];
  const float* bsig    = (const float*)d_in[13];
  const float* Wfeat   = (const float*)d_in[14];
  const float* bfeat   = (const float*)d_in[15];
  const float* Wc1     = (const float*)d_in[16];
  const float* bc1     = (const float*)d_in[17];
  const float* Wc2     = (const float*)d_in[18];
  const float* bc2     = (const float*)d_in[19];

  float* ws = (float*)d_ws;
  float* out = (float*)d_out;
  float* out_rgb = out;
  float* out_disp = out + NRAYS * 3;
  float* out_acc = out + NRAYS * 4;

  // prep threads: 8192 (Wcomb) + 2048 (WPE) + 64 (bcomb) + 2 = 10306
  hipLaunchKernelGGL(prep_kernel, dim3(41), dim3(256), 0, stream,
                     Wfeat, bfeat, Wc1, bc1, ws);
  hipLaunchKernelGGL(prep2_kernel, dim3(14), dim3(256), 0, stream, W1, W2, ws);
  hipLaunchKernelGGL(count_pe_kernel, dim3(NRAYS / 4), dim3(256), 0, stream,
                     rays_d, p2v, ws);
  hipLaunchKernelGGL(scan_kernel, dim3(1), dim3(1024), 0, stream, ws);
  hipLaunchKernelGGL(list_kernel, dim3(NRAYS / 4), dim3(256), 0, stream,
                     p2v, pts, ws);
  hipLaunchKernelGGL(mlp_mfma, dim3(NPTS / 64), dim3(128), 0, stream,
                     vox_emb, Wpts, b1, b2, Wsig, bsig, Wc2, bc2, ws);
  hipLaunchKernelGGL(repair_kernel, dim3(128), dim3(256), 0, stream,
                     pts, p2v, vox_emb, Wpts, W1, b1, W2, b2, Wsig, bsig, ws);
  hipLaunchKernelGGL(render_kernel, dim3(NRAYS / 4), dim3(256), 0, stream,
                     t_vals, dists, p2v, ws, out_rgb, out_disp, out_acc);
}